// Round 14
// baseline (564.929 us; speedup 1.0000x reference)
//
#include <hip/hip_runtime.h>
#include <hip/hip_bf16.h>

// Problem constants (reference: N,E,H,L = 64,64,768,512; eps=1e-12)
#define Nn 64
#define Ee 64
#define Hh 768
#define Ll 512
#define NEH (Nn * Ee * Hh) // 3145728 state elems
#define NEL (Nn * Ee * Ll) // 2097152 mapping elems

typedef __attribute__((ext_vector_type(8))) short bf16x8; // 8 bf16 = 4 VGPRs (MFMA A/B frag)
typedef __attribute__((ext_vector_type(4))) float f32x4;  // MFMA C/D frag

__device__ __forceinline__ unsigned short f2bf(float x) {
    union { __hip_bfloat16 b; unsigned short u; } cv;
    cv.b = __float2bfloat16(x);
    return cv.u;
}
__device__ __forceinline__ float bf2f(unsigned short u) {
    union { float f; unsigned int i; } v;
    v.i = ((unsigned int)u) << 16;
    return v.f;
}

// ---------------------------------------------------------------------------
// MEASUREMENT ROUND R14: exact R13 kernels, rep-wrapped so gram_pass (x6),
// quad_stats (x15) and gemm_store (x4) ALL out-rank the harness's 57-62us
// poison fills in the rocprof top-5. R13 cost 101.9us total vs a ~49us
// bottom-up model -- ~50us is unaccounted and must be localized before any
// further design work. Reps are idempotent; asm "memory" clobber prevents
// cross-rep elision.
// ---------------------------------------------------------------------------
__global__ __launch_bounds__(256) void cvt_transpose(
    const float* __restrict__ state, const float* __restrict__ mapping,
    __hip_bfloat16* __restrict__ sT, __hip_bfloat16* __restrict__ mT)
{
    __shared__ unsigned short lds[64][66]; // [x][e]

    int b = blockIdx.x;
    const float* src;
    __hip_bfloat16* dst;
    int W, x0;
    if (b < Nn * (Hh / 64)) {            // state tiles
        int n = b / (Hh / 64);
        x0 = (b % (Hh / 64)) * 64;
        src = state + (size_t)n * Ee * Hh;
        dst = sT + (size_t)n * Hh * Ee;
        W = Hh;
    } else {                              // mapping tiles
        b -= Nn * (Hh / 64);
        int n = b / (Ll / 64);
        x0 = (b % (Ll / 64)) * 64;
        src = mapping + (size_t)n * Ee * Ll;
        dst = mT + (size_t)n * Ll * Ee;
        W = Ll;
    }

    const int xr = (threadIdx.x & 31) * 2;
    const int er = threadIdx.x >> 5;  // 0..7
#pragma unroll
    for (int i = 0; i < 8; ++i) {
        int e = i * 8 + er;
        float2 v = *reinterpret_cast<const float2*>(src + (size_t)e * W + x0 + xr);
        lds[xr][e]     = f2bf(v.x);
        lds[xr + 1][e] = f2bf(v.y);
    }
    __syncthreads();

    const int e4 = (threadIdx.x & 15) * 4;
    const int xw = threadIdx.x >> 4;   // 0..15
    unsigned short* dsts = reinterpret_cast<unsigned short*>(dst);
#pragma unroll
    for (int i = 0; i < 4; ++i) {
        int x = i * 16 + xw;
        uint2 v;
        v.x = *reinterpret_cast<const unsigned int*>(&lds[x][e4]);
        v.y = *reinterpret_cast<const unsigned int*>(&lds[x][e4 + 2]);
        *reinterpret_cast<uint2*>(dsts + (size_t)(x0 + x) * Ee + e4) = v;
    }
}

// --------------------------- gram_pass x6 ----------------------------------
__global__ __launch_bounds__(256) void gram_pass(
    const float* __restrict__ state,  // [N][E][H]
    float* __restrict__ gram)         // [N][65][64]
{
    const int n    = blockIdx.x;
    const int tid  = threadIdx.x;
    const int w    = tid >> 6;
    const int lane = tid & 63;
    const int g    = lane >> 4;
    const int c    = lane & 15;
    const float* sn = state + (size_t)n * (Ee * Hh);
    float* Gn = gram + (size_t)n * (65 * 64);

    __shared__ float S1p[64][4];

#pragma unroll 1
    for (int rep = 0; rep < 6; ++rep) {
        asm volatile("" ::: "memory");
        __syncthreads();   // protect S1p reuse across reps

        f32x4 acc[4];
#pragma unroll
        for (int j = 0; j < 4; ++j) acc[j] = (f32x4){0.f, 0.f, 0.f, 0.f};

#pragma unroll 1
        for (int ks = 0; ks < 24; ++ks) {
            const int h0 = ks * 32 + g * 8;
            bf16x8 fa;
            {
                const float* p = sn + (size_t)(w * 16 + c) * Hh + h0;
                float4 a = *reinterpret_cast<const float4*>(p);
                float4 b = *reinterpret_cast<const float4*>(p + 4);
                fa[0] = (short)f2bf(a.x); fa[1] = (short)f2bf(a.y);
                fa[2] = (short)f2bf(a.z); fa[3] = (short)f2bf(a.w);
                fa[4] = (short)f2bf(b.x); fa[5] = (short)f2bf(b.y);
                fa[6] = (short)f2bf(b.z); fa[7] = (short)f2bf(b.w);
            }
#pragma unroll
            for (int j = 0; j < 4; ++j) {
                const float* p = sn + (size_t)(j * 16 + c) * Hh + h0;
                float4 a = *reinterpret_cast<const float4*>(p);
                float4 b = *reinterpret_cast<const float4*>(p + 4);
                bf16x8 fb;
                fb[0] = (short)f2bf(a.x); fb[1] = (short)f2bf(a.y);
                fb[2] = (short)f2bf(a.z); fb[3] = (short)f2bf(a.w);
                fb[4] = (short)f2bf(b.x); fb[5] = (short)f2bf(b.y);
                fb[6] = (short)f2bf(b.z); fb[7] = (short)f2bf(b.w);
                acc[j] = __builtin_amdgcn_mfma_f32_16x16x32_bf16(fa, fb, acc[j], 0, 0, 0);
            }
        }
#pragma unroll
        for (int j = 0; j < 4; ++j)
#pragma unroll
            for (int r = 0; r < 4; ++r)
                Gn[(w * 16 + g * 4 + r) * 64 + j * 16 + c] = acc[j][r];

        // S1
        {
            const int e  = tid >> 2;
            const int qt = tid & 3;
            const float* p = sn + (size_t)e * Hh + qt * 192;
            float s1 = 0.f;
#pragma unroll
            for (int i = 0; i < 48; ++i) {
                float4 v = *reinterpret_cast<const float4*>(p + i * 4);
                s1 += bf2f(f2bf(v.x)) + bf2f(f2bf(v.y)) + bf2f(f2bf(v.z)) + bf2f(f2bf(v.w));
            }
            S1p[e][qt] = s1;
        }
        __syncthreads();
        if (tid < 64)
            Gn[64 * 64 + tid] = S1p[tid][0] + S1p[tid][1] + S1p[tid][2] + S1p[tid][3];
    }
}

// --------------------------- quad_stats x15 --------------------------------
__global__ __launch_bounds__(64) void quad_stats(
    const float* __restrict__ gram,     // [N][65][64]
    const float* __restrict__ mapping,  // [N][E][L] fp32 original
    float2* __restrict__ stats)         // [N*L] = (mu, rstd)
{
    const int b = blockIdx.x;                 // 0..511
    const int n = b >> 3;
    const int l = ((b & 7) << 6) | threadIdx.x;
    const float* mp = mapping + (size_t)n * (Ee * Ll) + l;
    const float* G = gram + (size_t)n * (65 * 64);

#pragma unroll 1
    for (int rep = 0; rep < 15; ++rep) {
        asm volatile("" ::: "memory");

        float m[64];
#pragma unroll
        for (int e = 0; e < 64; ++e)
            m[e] = bf2f(f2bf(mp[(size_t)e * Ll]));

        float quad = 0.f;
#pragma unroll 1
        for (int e = 0; e < 64; ++e) {
            const float me = bf2f(f2bf(mp[(size_t)e * Ll]));
            const float* Ge = G + e * 64;
            float t0 = 0.f, t1 = 0.f, t2 = 0.f, t3 = 0.f;
#pragma unroll
            for (int e2 = 0; e2 < 64; e2 += 4) {
                t0 = fmaf(Ge[e2 + 0], m[e2 + 0], t0);
                t1 = fmaf(Ge[e2 + 1], m[e2 + 1], t1);
                t2 = fmaf(Ge[e2 + 2], m[e2 + 2], t2);
                t3 = fmaf(Ge[e2 + 3], m[e2 + 3], t3);
            }
            quad = fmaf(me, (t0 + t1) + (t2 + t3), quad);
        }
        float mus = 0.f;
        const float* S1 = G + 64 * 64;
#pragma unroll
        for (int e2 = 0; e2 < 64; ++e2)
            mus = fmaf(S1[e2], m[e2], mus);

        const float mu  = mus * (1.f / Hh);
        const float var = fmaxf(quad * (1.f / Hh) - mu * mu, 0.f);
        stats[n * Ll + l] = make_float2(mu, rsqrtf(var + 1e-12f));
    }
}

// --------------------------- gemm_store x4 ---------------------------------
__global__ __launch_bounds__(256) void gemm_store(
    const __hip_bfloat16* __restrict__ sT, // [N][H][E]
    const __hip_bfloat16* __restrict__ mT, // [N][L][E]
    const float2* __restrict__ stats,      // [N*L] = (mu, rstd)
    const float* __restrict__ gamma,
    const float* __restrict__ beta,
    float* __restrict__ out)               // [N][L][H]
{
    const int p    = blockIdx.x;
    const int n    = ((p >> 7) << 3) | (p & 7);
    const int l0   = ((p >> 3) & 15) << 5; // 32 rows per tile
    const int tid  = threadIdx.x;
    const int w    = tid >> 6;
    const int lane = tid & 63;
    const int g    = lane >> 4;
    const int c    = lane & 15;

#pragma unroll 1
    for (int rep = 0; rep < 4; ++rep) {
        asm volatile("" ::: "memory");

        bf16x8 b0[2], b1[2];
        float2 st[2];
        float* orow[2];
#pragma unroll
        for (int u = 0; u < 2; ++u) {
            const int l = l0 + u * 16 + c;
            const __hip_bfloat16* Brow = mT + (size_t)(n * Ll + l) * Ee + g * 8;
            b0[u] = *reinterpret_cast<const bf16x8*>(Brow);
            b1[u] = *reinterpret_cast<const bf16x8*>(Brow + 32);
            st[u] = stats[n * Ll + l];
            orow[u] = out + (size_t)(n * Ll + l) * Hh;
        }

        const __hip_bfloat16* Abase = sT + (size_t)(n * Hh + w * 192 + c) * Ee + g * 8;
#pragma unroll 1
        for (int t = 0; t < 12; ++t) {
            const __hip_bfloat16* ap = Abase + (size_t)t * 16 * Ee;
            bf16x8 a0 = *reinterpret_cast<const bf16x8*>(ap);
            bf16x8 a1 = *reinterpret_cast<const bf16x8*>(ap + 32);

            const int hb = w * 192 + t * 16 + g * 4;
            f32x4 gm = *reinterpret_cast<const f32x4*>(gamma + hb);
            f32x4 bt = *reinterpret_cast<const f32x4*>(beta + hb);

#pragma unroll
            for (int u = 0; u < 2; ++u) {
                f32x4 acc = (f32x4){0.f, 0.f, 0.f, 0.f};
                acc = __builtin_amdgcn_mfma_f32_16x16x32_bf16(a0, b0[u], acc, 0, 0, 0);
                acc = __builtin_amdgcn_mfma_f32_16x16x32_bf16(a1, b1[u], acc, 0, 0, 0);
                f32x4 v;
#pragma unroll
                for (int r = 0; r < 4; ++r)
                    v[r] = (acc[r] - st[u].x) * st[u].y * gm[r] + bt[r];
                *reinterpret_cast<f32x4*>(orow[u] + hb) = v;
            }
        }
    }
}

extern "C" void kernel_launch(void* const* d_in, const int* in_sizes, int n_in,
                              void* d_out, int out_size, void* d_ws, size_t ws_size,
                              hipStream_t stream)
{
    const float* state   = (const float*)d_in[0]; // (N,E,H)
    const float* mapping = (const float*)d_in[1]; // (N,E,L)
    const float* gamma   = (const float*)d_in[2]; // (H,)
    const float* beta    = (const float*)d_in[3]; // (H,)
    float* out           = (float*)d_out;         // (N,L,H)

    __hip_bfloat16* sT = (__hip_bfloat16*)d_ws;            // NEH bf16
    __hip_bfloat16* mT = sT + NEH;                         // NEL bf16
    float2* stats      = (float2*)((char*)d_ws + (size_t)(NEH + NEL) * 2); // N*L float2
    float*  gram       = (float*)((char*)stats + (size_t)Nn * Ll * sizeof(float2)); // N*65*64 f32

    const int tiles = Nn * (Hh / 64) + Nn * (Ll / 64); // 1280
    cvt_transpose<<<tiles, 256, 0, stream>>>(state, mapping, sT, mT);
    gram_pass<<<Nn, 256, 0, stream>>>(state, gram);
    quad_stats<<<Nn * (Ll / 64), 64, 0, stream>>>(gram, mapping, stats);
    gemm_store<<<Nn * (Ll / 32), 256, 0, stream>>>(sT, mT, stats, gamma, beta, out);
}

// Round 15
// 103.731 us; speedup vs baseline: 5.4461x; 5.4461x over previous
//
#include <hip/hip_runtime.h>
#include <hip/hip_bf16.h>

// Problem constants (reference: N,E,H,L = 64,64,768,512; eps=1e-12)
#define Nn 64
#define Ee 64
#define Hh 768
#define Ll 512
#define NEH (Nn * Ee * Hh) // 3145728 state elems
#define NEL (Nn * Ee * Ll) // 2097152 mapping elems
#define GSZ (65 * 64)      // per-n gram block: 64x64 G + row 64 = S1

typedef __attribute__((ext_vector_type(8))) short bf16x8; // 8 bf16 = 4 VGPRs (MFMA A/B frag)
typedef __attribute__((ext_vector_type(4))) float f32x4;  // MFMA C/D frag

__device__ __forceinline__ unsigned short f2bf(float x) {
    union { __hip_bfloat16 b; unsigned short u; } cv;
    cv.b = __float2bfloat16(x);
    return cv.u;
}
__device__ __forceinline__ float bf2f(unsigned short u) {
    union { float f; unsigned int i; } v;
    v.i = ((unsigned int)u) << 16;
    return v.f;
}
__device__ __forceinline__ float rnd_bf(float x) { return bf2f(f2bf(x)); }

// ---------------------------------------------------------------------------
// Pre-pass: fp32 -> bf16 convert + transpose, LDS-tiled (R3 form, ~6us).
// ---------------------------------------------------------------------------
__global__ __launch_bounds__(256) void cvt_transpose(
    const float* __restrict__ state, const float* __restrict__ mapping,
    __hip_bfloat16* __restrict__ sT, __hip_bfloat16* __restrict__ mT)
{
    __shared__ unsigned short lds[64][66]; // [x][e]

    int b = blockIdx.x;
    const float* src;
    __hip_bfloat16* dst;
    int W, x0;
    if (b < Nn * (Hh / 64)) {            // state tiles
        int n = b / (Hh / 64);
        x0 = (b % (Hh / 64)) * 64;
        src = state + (size_t)n * Ee * Hh;
        dst = sT + (size_t)n * Hh * Ee;
        W = Hh;
    } else {                              // mapping tiles
        b -= Nn * (Hh / 64);
        int n = b / (Ll / 64);
        x0 = (b % (Ll / 64)) * 64;
        src = mapping + (size_t)n * Ee * Ll;
        dst = mT + (size_t)n * Ll * Ee;
        W = Ll;
    }

    const int xr = (threadIdx.x & 31) * 2;
    const int er = threadIdx.x >> 5;  // 0..7
#pragma unroll
    for (int i = 0; i < 8; ++i) {
        int e = i * 8 + er;
        float2 v = *reinterpret_cast<const float2*>(src + (size_t)e * W + x0 + xr);
        lds[xr][e]     = f2bf(v.x);
        lds[xr + 1][e] = f2bf(v.y);
    }
    __syncthreads();

    const int e4 = (threadIdx.x & 15) * 4;
    const int xw = threadIdx.x >> 4;   // 0..15
    unsigned short* dsts = reinterpret_cast<unsigned short*>(dst);
#pragma unroll
    for (int i = 0; i < 4; ++i) {
        int x = i * 16 + xw;
        uint2 v;
        v.x = *reinterpret_cast<const unsigned int*>(&lds[x][e4]);
        v.y = *reinterpret_cast<const unsigned int*>(&lds[x][e4 + 2]);
        *reinterpret_cast<uint2*>(dsts + (size_t)(x0 + x) * Ee + e4) = v;
    }
}

// ---------------------------------------------------------------------------
// GRAM PASS (h-split x4): block b = (n, chunk); chunk covers 192 h.
// Partial G[e][e'] + S1[e] over its h range -> gram_part[b][65*64].
// 256 blocks (1/CU) instead of R13's 64 (75% CUs idle). 6 MFMA k-steps.
// Same f2bf rounding as main path; G symmetric => D-layout swap harmless.
// ---------------------------------------------------------------------------
__global__ __launch_bounds__(256) void gram_pass(
    const float* __restrict__ state,  // [N][E][H]
    float* __restrict__ gram_part)    // [N*4][65*64]
{
    const int b    = blockIdx.x;      // 0..255
    const int n    = b >> 2;
    const int ch   = b & 3;           // h-chunk: [ch*192, ch*192+192)
    const int tid  = threadIdx.x;
    const int w    = tid >> 6;
    const int lane = tid & 63;
    const int g    = lane >> 4;
    const int c    = lane & 15;
    const float* sn = state + (size_t)n * (Ee * Hh);
    float* Gp = gram_part + (size_t)b * GSZ;

    f32x4 acc[4];
#pragma unroll
    for (int j = 0; j < 4; ++j) acc[j] = (f32x4){0.f, 0.f, 0.f, 0.f};

#pragma unroll 1
    for (int ks = 0; ks < 6; ++ks) {
        const int h0 = ch * 192 + ks * 32 + g * 8;
        bf16x8 fa;
        {
            const float* p = sn + (size_t)(w * 16 + c) * Hh + h0;
            float4 a = *reinterpret_cast<const float4*>(p);
            float4 bb = *reinterpret_cast<const float4*>(p + 4);
            fa[0] = (short)f2bf(a.x);  fa[1] = (short)f2bf(a.y);
            fa[2] = (short)f2bf(a.z);  fa[3] = (short)f2bf(a.w);
            fa[4] = (short)f2bf(bb.x); fa[5] = (short)f2bf(bb.y);
            fa[6] = (short)f2bf(bb.z); fa[7] = (short)f2bf(bb.w);
        }
#pragma unroll
        for (int j = 0; j < 4; ++j) {
            const float* p = sn + (size_t)(j * 16 + c) * Hh + h0;
            float4 a = *reinterpret_cast<const float4*>(p);
            float4 bb = *reinterpret_cast<const float4*>(p + 4);
            bf16x8 fb;
            fb[0] = (short)f2bf(a.x);  fb[1] = (short)f2bf(a.y);
            fb[2] = (short)f2bf(a.z);  fb[3] = (short)f2bf(a.w);
            fb[4] = (short)f2bf(bb.x); fb[5] = (short)f2bf(bb.y);
            fb[6] = (short)f2bf(bb.z); fb[7] = (short)f2bf(bb.w);
            acc[j] = __builtin_amdgcn_mfma_f32_16x16x32_bf16(fa, fb, acc[j], 0, 0, 0);
        }
    }
#pragma unroll
    for (int j = 0; j < 4; ++j)
#pragma unroll
        for (int r = 0; r < 4; ++r)
            Gp[(w * 16 + g * 4 + r) * 64 + j * 16 + c] = acc[j][r];

    // S1 partial over this chunk
    __shared__ float S1p[64][4];
    {
        const int e  = tid >> 2;
        const int qt = tid & 3;
        const float* p = sn + (size_t)e * Hh + ch * 192 + qt * 48;
        float s1 = 0.f;
#pragma unroll
        for (int i = 0; i < 12; ++i) {
            float4 v = *reinterpret_cast<const float4*>(p + i * 4);
            s1 += rnd_bf(v.x) + rnd_bf(v.y) + rnd_bf(v.z) + rnd_bf(v.w);
        }
        S1p[e][qt] = s1;
    }
    __syncthreads();
    if (tid < 64)
        Gp[64 * 64 + tid] = (S1p[tid][0] + S1p[tid][1]) + (S1p[tid][2] + S1p[tid][3]);
}

// ---------------------------------------------------------------------------
// GRAM REDUCE: gram[n][i] = sum of 4 chunk partials. 266240 elems / 256.
// ---------------------------------------------------------------------------
__global__ __launch_bounds__(256) void gram_reduce(
    const float* __restrict__ gram_part, // [N*4][GSZ]
    float* __restrict__ gram)            // [N][GSZ]
{
    const int i = blockIdx.x * 256 + threadIdx.x;  // < Nn*GSZ = 266240
    const int n = i / GSZ;
    const int r = i - n * GSZ;
    const float* gp = gram_part + (size_t)n * 4 * GSZ + r;
    gram[i] = (gp[0] + gp[GSZ]) + (gp[2 * GSZ] + gp[3 * GSZ]);
}

// ---------------------------------------------------------------------------
// QUAD STATS v2: per (n,l): mu = (m^T S1)/H, E[x2] = (m^T G m)/H.
// R14 showed v1 at ~19us: 2 waves/CU, serial 1024-FMA chain. v2: 512 blocks
// x 256 threads (8 waves/CU); wave q computes the e in [q*16,q*16+16)
// partial; LDS reduce; wave 0 finishes with the S1 dot. All register arrays
// statically indexed (m[64] inner, me16[16] outer). G-row loads are wave-
// uniform -> scalar loads, overlapped across 4x more waves than v1.
// ---------------------------------------------------------------------------
__global__ __launch_bounds__(256) void quad_stats(
    const float* __restrict__ gram,     // [N][GSZ]
    const float* __restrict__ mapping,  // [N][E][L] fp32 original
    float2* __restrict__ stats)         // [N*L] = (mu, rstd)
{
    __shared__ float redP[4][64];

    const int b = blockIdx.x;           // 0..511
    const int n = b >> 3;
    const int l0 = (b & 7) << 6;
    const int tid = threadIdx.x;
    const int q = tid >> 6;             // wave 0..3 -> e quarter
    const int l = tid & 63;

    const float* mp = mapping + (size_t)n * (Ee * Ll) + l0 + l;
    const float* G  = gram + (size_t)n * GSZ;

    // full m vector (static reg indexing; loads coalesced across lanes)
    float m[64];
#pragma unroll
    for (int e = 0; e < 64; ++e)
        m[e] = rnd_bf(mp[(size_t)e * Ll]);

    // this wave's 16 outer coefficients (static: i is literal, q is addr-math)
    float me16[16];
#pragma unroll
    for (int i = 0; i < 16; ++i)
        me16[i] = rnd_bf(mp[(size_t)(q * 16 + i) * Ll]);

    float part = 0.f;
#pragma unroll
    for (int i = 0; i < 16; ++i) {
        const float* Ge = G + (q * 16 + i) * 64;   // wave-uniform -> s_load
        float t0 = 0.f, t1 = 0.f, t2 = 0.f, t3 = 0.f;
#pragma unroll
        for (int e2 = 0; e2 < 64; e2 += 4) {
            t0 = fmaf(Ge[e2 + 0], m[e2 + 0], t0);
            t1 = fmaf(Ge[e2 + 1], m[e2 + 1], t1);
            t2 = fmaf(Ge[e2 + 2], m[e2 + 2], t2);
            t3 = fmaf(Ge[e2 + 3], m[e2 + 3], t3);
        }
        part = fmaf(me16[i], (t0 + t1) + (t2 + t3), part);
    }
    redP[q][l] = part;
    __syncthreads();

    if (tid < 64) {   // wave 0: q==0, its m[] is the full vector for this l
        const float quad = (redP[0][l] + redP[1][l]) + (redP[2][l] + redP[3][l]);
        const float* S1 = G + 64 * 64;
        float mus = 0.f;
#pragma unroll
        for (int e = 0; e < 64; ++e)
            mus = fmaf(S1[e], m[e], mus);
        const float mu  = mus * (1.f / Hh);
        const float var = fmaxf(quad * (1.f / Hh) - mu * mu, 0.f);
        stats[n * Ll + l0 + l] = make_float2(mu, rsqrtf(var + 1e-12f));
    }
}

// ---------------------------------------------------------------------------
// MAIN PASS (R11/R13 gemm_store, verbatim): stats precomputed => each 16x16
// tile normalized + stored right after its 2 MFMAs; low regs, spread stores.
// ---------------------------------------------------------------------------
__global__ __launch_bounds__(256) void gemm_store(
    const __hip_bfloat16* __restrict__ sT, // [N][H][E]
    const __hip_bfloat16* __restrict__ mT, // [N][L][E]
    const float2* __restrict__ stats,      // [N*L] = (mu, rstd)
    const float* __restrict__ gamma,
    const float* __restrict__ beta,
    float* __restrict__ out)               // [N][L][H]
{
    const int p    = blockIdx.x;
    const int n    = ((p >> 7) << 3) | (p & 7);
    const int l0   = ((p >> 3) & 15) << 5; // 32 rows per tile
    const int tid  = threadIdx.x;
    const int w    = tid >> 6;
    const int lane = tid & 63;
    const int g    = lane >> 4;
    const int c    = lane & 15;

    bf16x8 b0[2], b1[2];
    float2 st[2];
    float* orow[2];
#pragma unroll
    for (int u = 0; u < 2; ++u) {
        const int l = l0 + u * 16 + c;
        const __hip_bfloat16* Brow = mT + (size_t)(n * Ll + l) * Ee + g * 8;
        b0[u] = *reinterpret_cast<const bf16x8*>(Brow);
        b1[u] = *reinterpret_cast<const bf16x8*>(Brow + 32);
        st[u] = stats[n * Ll + l];
        orow[u] = out + (size_t)(n * Ll + l) * Hh;
    }

    const __hip_bfloat16* Abase = sT + (size_t)(n * Hh + w * 192 + c) * Ee + g * 8;
#pragma unroll 1
    for (int t = 0; t < 12; ++t) {
        const __hip_bfloat16* ap = Abase + (size_t)t * 16 * Ee;
        bf16x8 a0 = *reinterpret_cast<const bf16x8*>(ap);
        bf16x8 a1 = *reinterpret_cast<const bf16x8*>(ap + 32);

        const int hb = w * 192 + t * 16 + g * 4;
        f32x4 gm = *reinterpret_cast<const f32x4*>(gamma + hb);
        f32x4 bt = *reinterpret_cast<const f32x4*>(beta + hb);

#pragma unroll
        for (int u = 0; u < 2; ++u) {
            f32x4 acc = (f32x4){0.f, 0.f, 0.f, 0.f};
            acc = __builtin_amdgcn_mfma_f32_16x16x32_bf16(a0, b0[u], acc, 0, 0, 0);
            acc = __builtin_amdgcn_mfma_f32_16x16x32_bf16(a1, b1[u], acc, 0, 0, 0);
            f32x4 v;
#pragma unroll
            for (int r = 0; r < 4; ++r)
                v[r] = (acc[r] - st[u].x) * st[u].y * gm[r] + bt[r];
            *reinterpret_cast<f32x4*>(orow[u] + hb) = v;
        }
    }
}

extern "C" void kernel_launch(void* const* d_in, const int* in_sizes, int n_in,
                              void* d_out, int out_size, void* d_ws, size_t ws_size,
                              hipStream_t stream)
{
    const float* state   = (const float*)d_in[0]; // (N,E,H)
    const float* mapping = (const float*)d_in[1]; // (N,E,L)
    const float* gamma   = (const float*)d_in[2]; // (H,)
    const float* beta    = (const float*)d_in[3]; // (H,)
    float* out           = (float*)d_out;         // (N,L,H)

    char* ws = (char*)d_ws;
    __hip_bfloat16* sT = (__hip_bfloat16*)ws;                 // NEH bf16
    __hip_bfloat16* mT = sT + NEH;                            // NEL bf16
    float2* stats   = (float2*)(ws + (size_t)(NEH + NEL) * 2);                 // N*L float2
    float* gram_prt = (float*)((char*)stats + (size_t)Nn * Ll * sizeof(float2)); // N*4*GSZ f32 (4.3MB)
    float* gram     = gram_prt + (size_t)Nn * 4 * GSZ;                           // N*GSZ f32 (1.1MB)
    // total ws use ~16.4 MB

    const int tiles = Nn * (Hh / 64) + Nn * (Ll / 64); // 1280
    cvt_transpose<<<tiles, 256, 0, stream>>>(state, mapping, sT, mT);
    gram_pass<<<Nn * 4, 256, 0, stream>>>(state, gram_prt);
    gram_reduce<<<(Nn * GSZ) / 256, 256, 0, stream>>>(gram_prt, gram);
    quad_stats<<<Nn * (Ll / 64), 256, 0, stream>>>(gram, mapping, stats);
    gemm_store<<<Nn * (Ll / 32), 256, 0, stream>>>(sT, mT, stats, gamma, beta, out);
}

// Round 16
// 53.134 us; speedup vs baseline: 10.6321x; 1.9522x over previous
//
#include <hip/hip_runtime.h>
#include <hip/hip_bf16.h>

// Problem constants (reference: N,E,H,L = 64,64,768,512; eps=1e-12)
#define Nn 64
#define Ee 64
#define Hh 768
#define Ll 512
#define NEH (Nn * Ee * Hh) // 3145728 state elems
#define NEL (Nn * Ee * Ll) // 2097152 mapping elems
#define GSZ (65 * 64)      // per-n gram partial block: 64x64 G + row 64 = S1

typedef __attribute__((ext_vector_type(8))) short bf16x8; // 8 bf16 (MFMA A/B frag)
typedef __attribute__((ext_vector_type(4))) short bf16x4; // 4 bf16 (8B)
typedef __attribute__((ext_vector_type(4))) float f32x4;  // MFMA C/D frag

__device__ __forceinline__ unsigned short f2bf(float x) {
    union { __hip_bfloat16 b; unsigned short u; } cv;
    cv.b = __float2bfloat16(x);
    return cv.u;
}
__device__ __forceinline__ float bf2f(unsigned short u) {
    union { float f; unsigned int i; } v;
    v.i = ((unsigned int)u) << 16;
    return v.f;
}

// ---------------------------------------------------------------------------
// Pre-pass: fp32 -> bf16 convert + transpose (R3 form) + NEW: state also gets
// a straight bf16 copy sC[n][e][h] (coalesced stores piggybacked on the
// coalesced read phase) so downstream gram MFMA needs no VALU conversion.
// ---------------------------------------------------------------------------
__global__ __launch_bounds__(256) void cvt_transpose(
    const float* __restrict__ state, const float* __restrict__ mapping,
    __hip_bfloat16* __restrict__ sT, __hip_bfloat16* __restrict__ mT,
    __hip_bfloat16* __restrict__ sC)
{
    __shared__ unsigned short lds[64][66]; // [x][e]

    int b = blockIdx.x;
    const float* src;
    __hip_bfloat16* dst;
    int W, x0, n;
    bool is_state;
    if (b < Nn * (Hh / 64)) {            // state tiles
        is_state = true;
        n = b / (Hh / 64);
        x0 = (b % (Hh / 64)) * 64;
        src = state + (size_t)n * Ee * Hh;
        dst = sT + (size_t)n * Hh * Ee;
        W = Hh;
    } else {                              // mapping tiles
        is_state = false;
        b -= Nn * (Hh / 64);
        n = b / (Ll / 64);
        x0 = (b % (Ll / 64)) * 64;
        src = mapping + (size_t)n * Ee * Ll;
        dst = mT + (size_t)n * Ll * Ee;
        W = Ll;
    }
    unsigned short* sCn = reinterpret_cast<unsigned short*>(sC) + (size_t)n * Ee * Hh;

    const int xr = (threadIdx.x & 31) * 2;
    const int er = threadIdx.x >> 5;  // 0..7
#pragma unroll
    for (int i = 0; i < 8; ++i) {
        int e = i * 8 + er;
        float2 v = *reinterpret_cast<const float2*>(src + (size_t)e * W + x0 + xr);
        unsigned short u0 = f2bf(v.x);
        unsigned short u1 = f2bf(v.y);
        lds[xr][e]     = u0;
        lds[xr + 1][e] = u1;
        if (is_state) {
            unsigned int pk = (unsigned int)u0 | ((unsigned int)u1 << 16);
            *reinterpret_cast<unsigned int*>(sCn + (size_t)e * Hh + x0 + xr) = pk;
        }
    }
    __syncthreads();

    const int e4 = (threadIdx.x & 15) * 4;
    const int xw = threadIdx.x >> 4;   // 0..15
    unsigned short* dsts = reinterpret_cast<unsigned short*>(dst);
#pragma unroll
    for (int i = 0; i < 4; ++i) {
        int x = i * 16 + xw;
        uint2 v;
        v.x = *reinterpret_cast<const unsigned int*>(&lds[x][e4]);
        v.y = *reinterpret_cast<const unsigned int*>(&lds[x][e4 + 2]);
        *reinterpret_cast<uint2*>(dsts + (size_t)(x0 + x) * Ee + e4) = v;
    }
}

// ---------------------------------------------------------------------------
// GRAM PASS v3: reads bf16 sC directly -> pure {16B loads + MFMA}, no cvt
// VALU (R15's v2 burned ~480 VALU/k-loop converting fp32). Block b=(n,chunk),
// chunk = 192 h = 6 k-steps. Partial G + S1 -> gram_part[b]. 256 blocks.
// G symmetric => any D-layout row/col swap is harmless here.
// ---------------------------------------------------------------------------
__global__ __launch_bounds__(256) void gram_pass(
    const __hip_bfloat16* __restrict__ sC,  // [N][E][H] bf16
    float* __restrict__ gram_part)          // [N*4][GSZ]
{
    const int b    = blockIdx.x;      // 0..255
    const int n    = b >> 2;
    const int ch   = b & 3;           // h-chunk: [ch*192, ch*192+192)
    const int tid  = threadIdx.x;
    const int w    = tid >> 6;
    const int lane = tid & 63;
    const int g    = lane >> 4;
    const int c    = lane & 15;
    const __hip_bfloat16* sn = sC + (size_t)n * (Ee * Hh);
    float* Gp = gram_part + (size_t)b * GSZ;

    f32x4 acc[4];
#pragma unroll
    for (int j = 0; j < 4; ++j) acc[j] = (f32x4){0.f, 0.f, 0.f, 0.f};

#pragma unroll
    for (int ks = 0; ks < 6; ++ks) {
        const int h0 = ch * 192 + ks * 32 + g * 8;
        bf16x8 fa = *reinterpret_cast<const bf16x8*>(sn + (size_t)(w * 16 + c) * Hh + h0);
#pragma unroll
        for (int j = 0; j < 4; ++j) {
            bf16x8 fb = *reinterpret_cast<const bf16x8*>(sn + (size_t)(j * 16 + c) * Hh + h0);
            acc[j] = __builtin_amdgcn_mfma_f32_16x16x32_bf16(fa, fb, acc[j], 0, 0, 0);
        }
    }
#pragma unroll
    for (int j = 0; j < 4; ++j)
#pragma unroll
        for (int r = 0; r < 4; ++r)
            Gp[(w * 16 + g * 4 + r) * 64 + j * 16 + c] = acc[j][r];

    // S1 partial over this chunk (48 h per thread, bf16 source)
    __shared__ float S1p[64][4];
    {
        const int e  = tid >> 2;
        const int qt = tid & 3;
        const unsigned short* p = reinterpret_cast<const unsigned short*>(sn)
                                  + (size_t)e * Hh + ch * 192 + qt * 48;
        float s1 = 0.f;
#pragma unroll
        for (int i = 0; i < 6; ++i) {
            bf16x8 v = *reinterpret_cast<const bf16x8*>(p + i * 8);
#pragma unroll
            for (int r = 0; r < 8; ++r) s1 += bf2f((unsigned short)v[r]);
        }
        S1p[e][qt] = s1;
    }
    __syncthreads();
    if (tid < 64)
        Gp[64 * 64 + tid] = (S1p[tid][0] + S1p[tid][1]) + (S1p[tid][2] + S1p[tid][3]);
}

// ---------------------------------------------------------------------------
// GRAM REDUCE: sum 4 chunk partials; G -> bf16 row-major (MFMA A-operand
// ready), S1 stays fp32.
// ---------------------------------------------------------------------------
__global__ __launch_bounds__(256) void gram_reduce(
    const float* __restrict__ gram_part,     // [N*4][GSZ]
    __hip_bfloat16* __restrict__ gbf,        // [N][64*64]
    float* __restrict__ s1f)                 // [N][64]
{
    const int i = blockIdx.x * 256 + threadIdx.x;  // < Nn*GSZ = 266240
    const int n = i / GSZ;
    const int r = i - n * GSZ;
    const float* p = gram_part + (size_t)n * 4 * GSZ + r;
    const float v = (p[0] + p[GSZ]) + (p[2 * GSZ] + p[3 * GSZ]);
    if (r < 4096) gbf[(size_t)n * 4096 + r] = __float2bfloat16(v);
    else          s1f[n * 64 + (r - 4096)] = v;
}

// ---------------------------------------------------------------------------
// QUAD STATS v3 -- MFMA this time (R14/R15: lane-serial GEMV was 19/59us).
// Per (n, 64 l's): T = G x M via 8 MFMA (A = G_bf16 rows, B = mT rows: the
// EXACT operand pattern verified in gemm_store), then per-lane dot
// sum_e m[e]*T[e,l] and sum_e S1[e]*m[e] in D-layout registers + 2 shuffles.
//   mu = S1.m/H,  E[x2] = m^T G m / H = sum_e m[e] T[e,l] / H.
// 512 blocks x 256 threads; ~8 MFMA + 14 loads per thread.
// ---------------------------------------------------------------------------
__global__ __launch_bounds__(256) void quad_stats(
    const __hip_bfloat16* __restrict__ gbf, // [N][64*64] row-major
    const float* __restrict__ s1f,          // [N][64]
    const __hip_bfloat16* __restrict__ mT,  // [N][L][E]
    float2* __restrict__ stats)             // [N*L] = (mu, rstd)
{
    const int b    = blockIdx.x;        // 0..511
    const int n    = b >> 3;
    const int l0   = (b & 7) << 6;      // 64 l per block
    const int tid  = threadIdx.x;
    const int w    = tid >> 6;          // wave -> 16-l tile
    const int lane = tid & 63;
    const int g    = lane >> 4;
    const int c    = lane & 15;

    const __hip_bfloat16* Gb = gbf + (size_t)n * 4096;
    const __hip_bfloat16* Mrow = mT + (size_t)(n * Ll + l0 + w * 16 + c) * Ee;

    const bf16x8 b0 = *reinterpret_cast<const bf16x8*>(Mrow + g * 8);
    const bf16x8 b1 = *reinterpret_cast<const bf16x8*>(Mrow + 32 + g * 8);

    f32x4 acc[4];
#pragma unroll
    for (int j = 0; j < 4; ++j) acc[j] = (f32x4){0.f, 0.f, 0.f, 0.f};

#pragma unroll
    for (int j = 0; j < 4; ++j) {
        bf16x8 a0 = *reinterpret_cast<const bf16x8*>(Gb + (size_t)(j * 16 + c) * 64 + g * 8);
        bf16x8 a1 = *reinterpret_cast<const bf16x8*>(Gb + (size_t)(j * 16 + c) * 64 + 32 + g * 8);
        acc[j] = __builtin_amdgcn_mfma_f32_16x16x32_bf16(a0, b0, acc[j], 0, 0, 0);
        acc[j] = __builtin_amdgcn_mfma_f32_16x16x32_bf16(a1, b1, acc[j], 0, 0, 0);
    }

    // Lane holds T[e = j*16 + g*4 + r, l = l0 + w*16 + c].
    float dot = 0.f, s1dot = 0.f;
    const float* S1 = s1f + n * 64;
#pragma unroll
    for (int j = 0; j < 4; ++j) {
        bf16x4 m4 = *reinterpret_cast<const bf16x4*>(Mrow + j * 16 + g * 4);
        f32x4 s4 = *reinterpret_cast<const f32x4*>(S1 + j * 16 + g * 4);
#pragma unroll
        for (int r = 0; r < 4; ++r) {
            float mv = bf2f((unsigned short)m4[r]);
            dot   = fmaf(acc[j][r], mv, dot);
            s1dot = fmaf(s4[r],     mv, s1dot);
        }
    }
    dot   += __shfl_xor(dot, 16, 64);
    dot   += __shfl_xor(dot, 32, 64);
    s1dot += __shfl_xor(s1dot, 16, 64);
    s1dot += __shfl_xor(s1dot, 32, 64);

    if (g == 0) {   // lane < 16
        const float mu  = s1dot * (1.f / Hh);
        const float var = fmaxf(dot * (1.f / Hh) - mu * mu, 0.f);
        stats[n * Ll + l0 + w * 16 + c] = make_float2(mu, rsqrtf(var + 1e-12f));
    }
}

// ---------------------------------------------------------------------------
// MAIN PASS (R11/R13 gemm_store, verbatim): stats precomputed => each 16x16
// tile normalized + stored right after its 2 MFMAs; low regs, no barriers,
// stores spread uniformly through the t-loop.
// ---------------------------------------------------------------------------
__global__ __launch_bounds__(256) void gemm_store(
    const __hip_bfloat16* __restrict__ sT, // [N][H][E]
    const __hip_bfloat16* __restrict__ mT, // [N][L][E]
    const float2* __restrict__ stats,      // [N*L] = (mu, rstd)
    const float* __restrict__ gamma,
    const float* __restrict__ beta,
    float* __restrict__ out)               // [N][L][H]
{
    const int p    = blockIdx.x;
    const int n    = ((p >> 7) << 3) | (p & 7);
    const int l0   = ((p >> 3) & 15) << 5; // 32 rows per tile
    const int tid  = threadIdx.x;
    const int w    = tid >> 6;
    const int lane = tid & 63;
    const int g    = lane >> 4;
    const int c    = lane & 15;

    bf16x8 b0[2], b1[2];
    float2 st[2];
    float* orow[2];
#pragma unroll
    for (int u = 0; u < 2; ++u) {
        const int l = l0 + u * 16 + c;
        const __hip_bfloat16* Brow = mT + (size_t)(n * Ll + l) * Ee + g * 8;
        b0[u] = *reinterpret_cast<const bf16x8*>(Brow);
        b1[u] = *reinterpret_cast<const bf16x8*>(Brow + 32);
        st[u] = stats[n * Ll + l];
        orow[u] = out + (size_t)(n * Ll + l) * Hh;
    }

    const __hip_bfloat16* Abase = sT + (size_t)(n * Hh + w * 192 + c) * Ee + g * 8;
#pragma unroll 1
    for (int t = 0; t < 12; ++t) {
        const __hip_bfloat16* ap = Abase + (size_t)t * 16 * Ee;
        bf16x8 a0 = *reinterpret_cast<const bf16x8*>(ap);
        bf16x8 a1 = *reinterpret_cast<const bf16x8*>(ap + 32);

        const int hb = w * 192 + t * 16 + g * 4;
        f32x4 gm = *reinterpret_cast<const f32x4*>(gamma + hb);
        f32x4 bt = *reinterpret_cast<const f32x4*>(beta + hb);

#pragma unroll
        for (int u = 0; u < 2; ++u) {
            f32x4 acc = (f32x4){0.f, 0.f, 0.f, 0.f};
            acc = __builtin_amdgcn_mfma_f32_16x16x32_bf16(a0, b0[u], acc, 0, 0, 0);
            acc = __builtin_amdgcn_mfma_f32_16x16x32_bf16(a1, b1[u], acc, 0, 0, 0);
            f32x4 v;
#pragma unroll
            for (int r = 0; r < 4; ++r)
                v[r] = (acc[r] - st[u].x) * st[u].y * gm[r] + bt[r];
            *reinterpret_cast<f32x4*>(orow[u] + hb) = v;
        }
    }
}

extern "C" void kernel_launch(void* const* d_in, const int* in_sizes, int n_in,
                              void* d_out, int out_size, void* d_ws, size_t ws_size,
                              hipStream_t stream)
{
    const float* state   = (const float*)d_in[0]; // (N,E,H)
    const float* mapping = (const float*)d_in[1]; // (N,E,L)
    const float* gamma   = (const float*)d_in[2]; // (H,)
    const float* beta    = (const float*)d_in[3]; // (H,)
    float* out           = (float*)d_out;         // (N,L,H)

    char* ws = (char*)d_ws;
    __hip_bfloat16* sT = (__hip_bfloat16*)ws;                       // NEH bf16
    __hip_bfloat16* mT = sT + NEH;                                  // NEL bf16
    __hip_bfloat16* sC = mT + NEL;                                  // NEH bf16
    char* ws2 = ws + (size_t)(NEH + NEL + NEH) * 2;
    float2* stats   = (float2*)ws2;                                  // N*L float2
    float* gram_prt = (float*)(ws2 + (size_t)Nn * Ll * sizeof(float2)); // N*4*GSZ f32
    __hip_bfloat16* gbf = (__hip_bfloat16*)((char*)gram_prt + (size_t)Nn * 4 * GSZ * 4); // N*4096 bf16
    float* s1f = (float*)((char*)gbf + (size_t)Nn * 4096 * 2);       // N*64 f32
    // total ws use ~22 MB

    const int tiles = Nn * (Hh / 64) + Nn * (Ll / 64); // 1280
    cvt_transpose<<<tiles, 256, 0, stream>>>(state, mapping, sT, mT, sC);
    gram_pass<<<Nn * 4, 256, 0, stream>>>(sC, gram_prt);
    gram_reduce<<<(Nn * GSZ) / 256, 256, 0, stream>>>(gram_prt, gbf, s1f);
    quad_stats<<<Nn * (Ll / 64), 256, 0, stream>>>(gbf, s1f, mT, stats);
    gemm_store<<<Nn * (Ll / 32), 256, 0, stream>>>(sT, mT, stats, gamma, beta, out);
}